// Round 11
// baseline (185.669 us; speedup 1.0000x reference)
//
#include <hip/hip_runtime.h>
#include <hip/hip_bf16.h>

#define D_MODEL 768
#define D_HIDDEN 2048
#define NHEADS 12
#define BATCH 4
#define SEQ 128
#define MROWS (BATCH*SEQ)                      // 512
#define SCORE_ELEMS (BATCH*NHEADS*SEQ*SEQ)     // 786432
#define REG_OFF SCORE_ELEMS
#define FIRES_OFF (SCORE_ELEMS + 1)
#define NROWS_T 65536                          // fires rows (b,q,k)
#define FIRES_WAVES 2048
#define FIRES_BLOCKS 512
#define SCORE_BLOCKS (BATCH*NHEADS*16)         // 768
#define TRIGCAP 64

typedef __attribute__((ext_vector_type(8))) short bf16x8;
typedef __attribute__((ext_vector_type(4))) float f32x4;

static __device__ __forceinline__ unsigned short f2bf(float f) {
    union { float f; unsigned u; } v; v.f = f;
    unsigned u = v.u;
    return (unsigned short)((u + 0x7FFFu + ((u >> 16) & 1u)) >> 16);  // RNE
}

// split v (fp32) into bf16 hi + bf16 lo with v ~ hi + lo to ~2^-18 relative.
static __device__ __forceinline__ void split_bf16(float v, short& hi, short& lo) {
    unsigned short h = f2bf(v);
    float hf = __uint_as_float((unsigned)h << 16);
    float lf = v - hf;
    hi = (short)h;
    lo = (short)f2bf(lf);
}

static __device__ __forceinline__ float fsqrt_fast(float x) {
    return __builtin_amdgcn_sqrtf(x);      // raw v_sqrt_f32 (reg_loss tol 2%)
}

// ---------------------------------------------------------------------------
// Kernel 1: encoder GEMM via SPLIT-BF16 MFMA + INLINE block-local fp64 fix.
// out = relu(x @ W + b); acc += xh*wh + xh*wl + xl*wh (missing xl*wl ~2e-5).
// Near-zero preacts (|pre|<3e-4) go to an LDS list; at block end all 256
// threads cooperatively recompute each in fp64 (3 terms/thread + reduce).
// Block (0,0,0) zeroes out[REG_OFF]. Grid (32, 8, 2) = 512 blocks.
// ---------------------------------------------------------------------------
__global__ __launch_bounds__(256) void enc_kernel(
    const float* __restrict__ x,
    const float* __restrict__ WQ, const float* __restrict__ WK,
    const float* __restrict__ bQ, const float* __restrict__ bK,
    float* __restrict__ qbuf, float* __restrict__ kbuf,
    float* __restrict__ out)
{
    __shared__ unsigned tcnt;
    __shared__ unsigned tlist[TRIGCAP];
    __shared__ double   redd[4];

    const int bufid = blockIdx.z;
    const float* W    = bufid ? WK : WQ;
    const float* bias = bufid ? bK : bQ;
    float* outbuf     = bufid ? kbuf : qbuf;

    const int t  = threadIdx.x;
    if (t == 0) tcnt = 0u;
    if (blockIdx.x == 0 && blockIdx.y == 0 && blockIdx.z == 0 && t == 0)
        out[REG_OFF] = 0.f;
    __syncthreads();

    const int w  = t >> 6;
    const int l  = t & 63;
    const int mt = blockIdx.y * 64 + (w >> 1) * 32;
    const int nt = blockIdx.x * 64 + (w & 1) * 32;
    const int lr = l & 15;
    const int hg = (l >> 4) * 8;

    f32x4 acc[2][2];
    #pragma unroll
    for (int i = 0; i < 2; ++i)
        #pragma unroll
        for (int j = 0; j < 2; ++j) { f32x4 z = {0.f, 0.f, 0.f, 0.f}; acc[i][j] = z; }

    for (int kk = 0; kk < D_MODEL; kk += 32) {
        const int h0 = kk + hg;
        bf16x8 ah[2], al[2], bh[2], bl[2];
        #pragma unroll
        for (int fi = 0; fi < 2; ++fi) {
            const float* xp = x + (size_t)(mt + fi * 16 + lr) * D_MODEL + h0;
            const float4 v1 = *reinterpret_cast<const float4*>(xp);
            const float4 v2 = *reinterpret_cast<const float4*>(xp + 4);
            const float vv[8] = {v1.x, v1.y, v1.z, v1.w, v2.x, v2.y, v2.z, v2.w};
            #pragma unroll
            for (int i = 0; i < 8; ++i) {
                short h_, lo_;
                split_bf16(vv[i], h_, lo_);
                ah[fi][i] = h_; al[fi][i] = lo_;
            }
        }
        #pragma unroll
        for (int fj = 0; fj < 2; ++fj) {
            const int col = nt + fj * 16 + lr;
            #pragma unroll
            for (int i = 0; i < 8; ++i) {
                short h_, lo_;
                split_bf16(W[(size_t)(h0 + i) * D_HIDDEN + col], h_, lo_);
                bh[fj][i] = h_; bl[fj][i] = lo_;
            }
        }
        #pragma unroll
        for (int fi = 0; fi < 2; ++fi)
            #pragma unroll
            for (int fj = 0; fj < 2; ++fj) {
                acc[fi][fj] = __builtin_amdgcn_mfma_f32_16x16x32_bf16(
                    ah[fi], bh[fj], acc[fi][fj], 0, 0, 0);
                acc[fi][fj] = __builtin_amdgcn_mfma_f32_16x16x32_bf16(
                    ah[fi], bl[fj], acc[fi][fj], 0, 0, 0);
                acc[fi][fj] = __builtin_amdgcn_mfma_f32_16x16x32_bf16(
                    al[fi], bh[fj], acc[fi][fj], 0, 0, 0);
            }
    }

    #pragma unroll
    for (int fi = 0; fi < 2; ++fi)
        #pragma unroll
        for (int fj = 0; fj < 2; ++fj)
            #pragma unroll
            for (int j = 0; j < 4; ++j) {
                const int row = mt + fi * 16 + (l >> 4) * 4 + j;
                const int col = nt + fj * 16 + lr;
                float pre = acc[fi][fj][j] + bias[col];
                if (fabsf(pre) < 3e-4f) {
                    unsigned idx = atomicAdd(&tcnt, 1u);
                    if (idx < TRIGCAP) {
                        tlist[idx] = ((unsigned)row << 11) | (unsigned)col;
                    } else {
                        const float* xr = x + (size_t)row * D_MODEL;
                        const float* wc = W + col;
                        double s = (double)bias[col];
                        for (int dd = 0; dd < D_MODEL; ++dd)
                            s += (double)xr[dd] * (double)wc[(size_t)dd * D_HIDDEN];
                        pre = (float)s;
                    }
                }
                outbuf[(size_t)row * D_HIDDEN + col] = fmaxf(pre, 0.f);
            }

    __syncthreads();
    const unsigned n = min(tcnt, (unsigned)TRIGCAP);
    for (unsigned i = 0; i < n; ++i) {
        const unsigned e = tlist[i];
        const int hh = (int)(e & 2047u);
        const int mm = (int)(e >> 11);
        double s = 0.0;
        #pragma unroll
        for (int k = 0; k < 3; ++k) {
            const int dd = t + k * 256;
            s += (double)x[(size_t)mm * D_MODEL + dd]
               * (double)W[(size_t)dd * D_HIDDEN + hh];
        }
        #pragma unroll
        for (int off = 32; off > 0; off >>= 1) s += __shfl_down(s, off);
        if (l == 0) redd[w] = s;
        __syncthreads();
        if (t == 0) {
            double tot = redd[0] + redd[1] + redd[2] + redd[3] + (double)bias[hh];
            outbuf[(size_t)mm * D_HIDDEN + hh] = fmaxf((float)tot, 0.f);
        }
        __syncthreads();
    }
}

// ---------------------------------------------------------------------------
// Kernel 2: COMBINED score (blocks < 768) + fires (blocks 768..1279).
//
// Fires: dense moving front + PLAIN CACHED f32x4 stores (A/B vs R10's NT:
// per-step read set is only 16 q-rows = 128 KB, so there is nothing for NT
// to protect, and NT's 16B granules forfeit L2 line-merge -- the R4 lesson).
// k-row register caching (constant for 8 steps); -1-shifted 16B-aligned
// stores; shfl neighbor machinery; R==0 corner split to scalars so
// out[REG_OFF] is never touched. reg partial -> one atomicAdd per block.
// ---------------------------------------------------------------------------
__global__ __launch_bounds__(256) void main_kernel(
    const float* __restrict__ qbuf, const float* __restrict__ kbuf,
    const float* __restrict__ Wdec, const float* __restrict__ bdec,
    float* __restrict__ out)
{
    __shared__ float wcol[D_HIDDEN];
    __shared__ float red[4][64][16];
    __shared__ float rs[4];
    const int t  = threadIdx.x;
    const int bi = blockIdx.x;

    if (bi < SCORE_BLOCKS) {
        // ----------------------------- score -----------------------------
        const int sub = bi & 15;
        const int pr  = bi >> 4;
        const int n   = pr % NHEADS;
        const int b   = pr / NHEADS;

        for (int idx = t; idx < D_HIDDEN; idx += 256)
            wcol[idx] = Wdec[(size_t)idx * NHEADS + n];
        __syncthreads();

        const int qt   = (sub >> 2) * 32;
        const int kt   = (sub & 3) * 32;
        const int w    = t >> 6;
        const int lane = t & 63;
        const int lrow = lane & 15;
        const int koff = (lane >> 4) * 8;

        f32x4 acc[2][2];
        #pragma unroll
        for (int i = 0; i < 2; ++i)
            #pragma unroll
            for (int j = 0; j < 2; ++j) { f32x4 z = {0.f, 0.f, 0.f, 0.f}; acc[i][j] = z; }

        const float* qb = qbuf + (size_t)b * SEQ * D_HIDDEN;
        const float* kb = kbuf + (size_t)b * SEQ * D_HIDDEN;

        const int hlo = w * 512;
        for (int kk = hlo; kk < hlo + 512; kk += 32) {
            const int h0 = kk + koff;
            float wv[8];
            #pragma unroll
            for (int i = 0; i < 8; ++i) wv[i] = wcol[h0 + i];

            bf16x8 afrag[2], bfrag[2];
            #pragma unroll
            for (int fi = 0; fi < 2; ++fi) {
                const float* qp = qb + (size_t)(qt + fi * 16 + lrow) * D_HIDDEN + h0;
                const float4 q1 = *reinterpret_cast<const float4*>(qp);
                const float4 q2 = *reinterpret_cast<const float4*>(qp + 4);
                const float qf[8] = {q1.x, q1.y, q1.z, q1.w, q2.x, q2.y, q2.z, q2.w};
                #pragma unroll
                for (int i = 0; i < 8; ++i) afrag[fi][i] = (short)f2bf(qf[i] * wv[i]);
            }
            #pragma unroll
            for (int fj = 0; fj < 2; ++fj) {
                const float* kp = kb + (size_t)(kt + fj * 16 + lrow) * D_HIDDEN + h0;
                const float4 k1 = *reinterpret_cast<const float4*>(kp);
                const float4 k2 = *reinterpret_cast<const float4*>(kp + 4);
                const float kf[8] = {k1.x, k1.y, k1.z, k1.w, k2.x, k2.y, k2.z, k2.w};
                #pragma unroll
                for (int i = 0; i < 8; ++i) bfrag[fj][i] = (short)f2bf(kf[i]);
            }
            #pragma unroll
            for (int fi = 0; fi < 2; ++fi)
                #pragma unroll
                for (int fj = 0; fj < 2; ++fj)
                    acc[fi][fj] = __builtin_amdgcn_mfma_f32_16x16x32_bf16(
                        afrag[fi], bfrag[fj], acc[fi][fj], 0, 0, 0);
        }

        #pragma unroll
        for (int fi = 0; fi < 2; ++fi)
            #pragma unroll
            for (int fj = 0; fj < 2; ++fj)
                #pragma unroll
                for (int j = 0; j < 4; ++j)
                    red[w][lane][fi * 8 + fj * 4 + j] = acc[fi][fj][j];
        __syncthreads();

        const float bd   = bdec[n];
        const int   outb = (b * NHEADS + n) * SEQ * SEQ;
        #pragma unroll
        for (int u = 0; u < 4; ++u) {
            const int j = w * 4 + u;
            const float s = (red[0][lane][j] + red[1][lane][j])
                          + (red[2][lane][j] + red[3][lane][j]);
            const int fi = j >> 3, fj = (j >> 2) & 1, jj = j & 3;
            const int row = qt + fi * 16 + (lane >> 4) * 4 + jj;
            const int col = kt + fj * 16 + (lane & 15);
            out[outb + row * SEQ + col] = s * 0.125f + bd;
        }
        return;
    }

    // ------------------------------- fires -------------------------------
    const int w  = t >> 6;
    const int l  = t & 63;
    const int g  = (bi - SCORE_BLOCKS) * 4 + w;           // 0..2047
    const int g7 = g >> 7;                                 // 0..15
    const int gk = g & 127;

    f32x4* out4 = reinterpret_cast<f32x4*>(out + FIRES_OFF - 1);  // 16B aligned
    float racc = 0.f;

    #pragma unroll 1
    for (int b = 0; b < 4; ++b) {
        const float* kr = kbuf + ((size_t)(b * SEQ) + gk) * D_HIDDEN;
        f32x4 kv[8];
        #pragma unroll
        for (int j = 0; j < 8; ++j)
            kv[j] = *reinterpret_cast<const f32x4*>(kr + 256 * j + 4 * l);
        float k3[8], k63[8];
        #pragma unroll
        for (int j = 0; j < 8; ++j) {
            k3[j]  = __shfl_up(kv[j][3], 1);
            k63[j] = __shfl(kv[j][3], 63);
        }

        #pragma unroll 1
        for (int ss = 0; ss < 8; ++ss) {
            const int s    = b * 8 + ss;
            const int R    = g + s * FIRES_WAVES;
            const int brow = s * 16 + g7;                  // R >> 7
            const float* qr = qbuf + (size_t)brow * D_HIDDEN;

            f32x4 qv[8];
            #pragma unroll
            for (int j = 0; j < 8; ++j)
                qv[j] = *reinterpret_cast<const f32x4*>(qr + 256 * j + 4 * l);

            float pm1 = 0.f;
            if (l == 0 && R > 0) {
                const int pbrow = (R - 1) >> 7;
                const int pb    = pbrow >> 7;
                const int pkrow = (pb << 7) + ((R - 1) & 127);
                pm1 = qbuf[(size_t)pbrow * D_HIDDEN + 2047]
                    * kbuf[(size_t)pkrow * D_HIDDEN + 2047];
            }

            float q3[8], q63[8];
            #pragma unroll
            for (int j = 0; j < 8; ++j) {
                q3[j]  = __shfl_up(qv[j][3], 1);
                q63[j] = __shfl(qv[j][3], 63);
            }

            #pragma unroll
            for (int j = 0; j < 8; ++j) {
                float p0;
                if (l == 0) {
                    p0 = (j == 0) ? pm1 : q63[j - 1] * k63[j - 1];
                } else {
                    p0 = q3[j] * k3[j];
                }
                const float p1 = qv[j][0] * kv[j][0];
                const float p2 = qv[j][1] * kv[j][1];
                const float p3 = qv[j][2] * kv[j][2];
                f32x4 f;
                f[0] = (p0 > 0.f) ? 1.f : 0.f;
                f[1] = (p1 > 0.f) ? 1.f : 0.f;
                f[2] = (p2 > 0.f) ? 1.f : 0.f;
                f[3] = (p3 > 0.f) ? 1.f : 0.f;
                if (R == 0 && j == 0 && l == 0) {
                    out[FIRES_OFF + 0] = f[1];
                    out[FIRES_OFF + 1] = f[2];
                    out[FIRES_OFF + 2] = f[3];
                } else {
                    out4[(size_t)R * 512 + 64 * j + l] = f;
                }
                racc += (fsqrt_fast(p0 + 1e-6f) + fsqrt_fast(p1 + 1e-6f))
                      + (fsqrt_fast(p2 + 1e-6f) + fsqrt_fast(p3 + 1e-6f));
            }
        }
    }

    // exclude the fake first slot's sqrt (R=0, j=0, l=0, p0 = 0)
    if (g == 0 && l == 0) racc -= fsqrt_fast(1e-6f);
    // global-last element (row 65535, h=2047)
    if (g == FIRES_WAVES - 1 && l == 0) {
        const float pv = qbuf[(size_t)511 * D_HIDDEN + 2047]
                       * kbuf[(size_t)511 * D_HIDDEN + 2047];
        out[(size_t)(FIRES_OFF - 1) + (size_t)NROWS_T * D_HIDDEN] = (pv > 0.f) ? 1.f : 0.f;
        racc += fsqrt_fast(pv + 1e-6f);
    }

    #pragma unroll
    for (int off = 32; off > 0; off >>= 1) racc += __shfl_down(racc, off);
    if (l == 0) rs[w] = racc;
    __syncthreads();
    if (t == 0)
        atomicAdd(out + REG_OFF, ((rs[0] + rs[1]) + (rs[2] + rs[3])) * 1e-3f);
}

// ---------------------------------------------------------------------------
extern "C" void kernel_launch(void* const* d_in, const int* in_sizes, int n_in,
                              void* d_out, int out_size, void* d_ws, size_t ws_size,
                              hipStream_t stream) {
    const float* x  = (const float*)d_in[0];
    const float* WQ = (const float*)d_in[1];
    const float* WK = (const float*)d_in[2];
    const float* bQ = (const float*)d_in[3];
    const float* bK = (const float*)d_in[4];
    const float* Wd = (const float*)d_in[5];
    const float* bd = (const float*)d_in[6];
    float* out  = (float*)d_out;
    float* qbuf = (float*)d_ws;                                // 4 MB
    float* kbuf = qbuf + (size_t)MROWS * D_HIDDEN;             // 4 MB

    dim3 b256(256);

    enc_kernel<<<dim3(D_HIDDEN / 64, MROWS / 64, 2), b256, 0, stream>>>(
        x, WQ, WK, bQ, bK, qbuf, kbuf, out);

    main_kernel<<<dim3(SCORE_BLOCKS + FIRES_BLOCKS), b256, 0, stream>>>(
        qbuf, kbuf, Wd, bd, out);
}

// Round 12
// 184.895 us; speedup vs baseline: 1.0042x; 1.0042x over previous
//
#include <hip/hip_runtime.h>
#include <hip/hip_bf16.h>

#define D_MODEL 768
#define D_HIDDEN 2048
#define NHEADS 12
#define BATCH 4
#define SEQ 128
#define MROWS (BATCH*SEQ)                      // 512
#define SCORE_ELEMS (BATCH*NHEADS*SEQ*SEQ)     // 786432
#define REG_OFF SCORE_ELEMS
#define FIRES_OFF (SCORE_ELEMS + 1)
#define NROWS_T 65536                          // fires rows (b,q,k)
#define FIRES_WAVES 8192
#define FIRES_BLOCKS 2048
#define SCORE_BLOCKS (BATCH*NHEADS*16)         // 768
#define TRIGCAP 64

typedef __attribute__((ext_vector_type(8))) short bf16x8;
typedef __attribute__((ext_vector_type(4))) float f32x4;

static __device__ __forceinline__ unsigned short f2bf(float f) {
    union { float f; unsigned u; } v; v.f = f;
    unsigned u = v.u;
    return (unsigned short)((u + 0x7FFFu + ((u >> 16) & 1u)) >> 16);  // RNE
}

// split v (fp32) into bf16 hi + bf16 lo with v ~ hi + lo to ~2^-18 relative.
static __device__ __forceinline__ void split_bf16(float v, short& hi, short& lo) {
    unsigned short h = f2bf(v);
    float hf = __uint_as_float((unsigned)h << 16);
    float lf = v - hf;
    hi = (short)h;
    lo = (short)f2bf(lf);
}

static __device__ __forceinline__ float fsqrt_fast(float x) {
    return __builtin_amdgcn_sqrtf(x);      // raw v_sqrt_f32 (reg_loss tol 2%)
}

// ---------------------------------------------------------------------------
// Kernel 1: encoder GEMM via SPLIT-BF16 MFMA + INLINE block-local fp64 fix.
// out = relu(x @ W + b); acc += xh*wh + xh*wl + xl*wh (missing xl*wl ~2e-5).
// Near-zero preacts (|pre|<3e-4) go to an LDS list; at block end all 256
// threads cooperatively recompute each in fp64 (3 terms/thread + reduce).
// Block (0,0,0) zeroes out[REG_OFF]. Grid (32, 8, 2) = 512 blocks.
// ---------------------------------------------------------------------------
__global__ __launch_bounds__(256) void enc_kernel(
    const float* __restrict__ x,
    const float* __restrict__ WQ, const float* __restrict__ WK,
    const float* __restrict__ bQ, const float* __restrict__ bK,
    float* __restrict__ qbuf, float* __restrict__ kbuf,
    float* __restrict__ out)
{
    __shared__ unsigned tcnt;
    __shared__ unsigned tlist[TRIGCAP];
    __shared__ double   redd[4];

    const int bufid = blockIdx.z;
    const float* W    = bufid ? WK : WQ;
    const float* bias = bufid ? bK : bQ;
    float* outbuf     = bufid ? kbuf : qbuf;

    const int t  = threadIdx.x;
    if (t == 0) tcnt = 0u;
    if (blockIdx.x == 0 && blockIdx.y == 0 && blockIdx.z == 0 && t == 0)
        out[REG_OFF] = 0.f;
    __syncthreads();

    const int w  = t >> 6;
    const int l  = t & 63;
    const int mt = blockIdx.y * 64 + (w >> 1) * 32;
    const int nt = blockIdx.x * 64 + (w & 1) * 32;
    const int lr = l & 15;
    const int hg = (l >> 4) * 8;

    f32x4 acc[2][2];
    #pragma unroll
    for (int i = 0; i < 2; ++i)
        #pragma unroll
        for (int j = 0; j < 2; ++j) { f32x4 z = {0.f, 0.f, 0.f, 0.f}; acc[i][j] = z; }

    for (int kk = 0; kk < D_MODEL; kk += 32) {
        const int h0 = kk + hg;
        bf16x8 ah[2], al[2], bh[2], bl[2];
        #pragma unroll
        for (int fi = 0; fi < 2; ++fi) {
            const float* xp = x + (size_t)(mt + fi * 16 + lr) * D_MODEL + h0;
            const float4 v1 = *reinterpret_cast<const float4*>(xp);
            const float4 v2 = *reinterpret_cast<const float4*>(xp + 4);
            const float vv[8] = {v1.x, v1.y, v1.z, v1.w, v2.x, v2.y, v2.z, v2.w};
            #pragma unroll
            for (int i = 0; i < 8; ++i) {
                short h_, lo_;
                split_bf16(vv[i], h_, lo_);
                ah[fi][i] = h_; al[fi][i] = lo_;
            }
        }
        #pragma unroll
        for (int fj = 0; fj < 2; ++fj) {
            const int col = nt + fj * 16 + lr;
            #pragma unroll
            for (int i = 0; i < 8; ++i) {
                short h_, lo_;
                split_bf16(W[(size_t)(h0 + i) * D_HIDDEN + col], h_, lo_);
                bh[fj][i] = h_; bl[fj][i] = lo_;
            }
        }
        #pragma unroll
        for (int fi = 0; fi < 2; ++fi)
            #pragma unroll
            for (int fj = 0; fj < 2; ++fj) {
                acc[fi][fj] = __builtin_amdgcn_mfma_f32_16x16x32_bf16(
                    ah[fi], bh[fj], acc[fi][fj], 0, 0, 0);
                acc[fi][fj] = __builtin_amdgcn_mfma_f32_16x16x32_bf16(
                    ah[fi], bl[fj], acc[fi][fj], 0, 0, 0);
                acc[fi][fj] = __builtin_amdgcn_mfma_f32_16x16x32_bf16(
                    al[fi], bh[fj], acc[fi][fj], 0, 0, 0);
            }
    }

    #pragma unroll
    for (int fi = 0; fi < 2; ++fi)
        #pragma unroll
        for (int fj = 0; fj < 2; ++fj)
            #pragma unroll
            for (int j = 0; j < 4; ++j) {
                const int row = mt + fi * 16 + (l >> 4) * 4 + j;
                const int col = nt + fj * 16 + lr;
                float pre = acc[fi][fj][j] + bias[col];
                if (fabsf(pre) < 3e-4f) {
                    unsigned idx = atomicAdd(&tcnt, 1u);
                    if (idx < TRIGCAP) {
                        tlist[idx] = ((unsigned)row << 11) | (unsigned)col;
                    } else {
                        const float* xr = x + (size_t)row * D_MODEL;
                        const float* wc = W + col;
                        double s = (double)bias[col];
                        for (int dd = 0; dd < D_MODEL; ++dd)
                            s += (double)xr[dd] * (double)wc[(size_t)dd * D_HIDDEN];
                        pre = (float)s;
                    }
                }
                outbuf[(size_t)row * D_HIDDEN + col] = fmaxf(pre, 0.f);
            }

    __syncthreads();
    const unsigned n = min(tcnt, (unsigned)TRIGCAP);
    for (unsigned i = 0; i < n; ++i) {
        const unsigned e = tlist[i];
        const int hh = (int)(e & 2047u);
        const int mm = (int)(e >> 11);
        double s = 0.0;
        #pragma unroll
        for (int k = 0; k < 3; ++k) {
            const int dd = t + k * 256;
            s += (double)x[(size_t)mm * D_MODEL + dd]
               * (double)W[(size_t)dd * D_HIDDEN + hh];
        }
        #pragma unroll
        for (int off = 32; off > 0; off >>= 1) s += __shfl_down(s, off);
        if (l == 0) redd[w] = s;
        __syncthreads();
        if (t == 0) {
            double tot = redd[0] + redd[1] + redd[2] + redd[3] + (double)bias[hh];
            outbuf[(size_t)mm * D_HIDDEN + hh] = fmaxf((float)tot, 0.f);
        }
        __syncthreads();
    }
}

// ---------------------------------------------------------------------------
// Kernel 2: COMBINED score (blocks < 768) + fires (blocks 768..2815).
//
// Fires: dense moving front + NT stores (A/B-proven +10us vs cached, R10/R11)
// + 4x WAVE COUNT (8192 waves, 8 rows each): the fill kernel sustains
// 6.7 TB/s with ~8192 pure-store waves; at 2048 waves our loads/VALU between
// stores drop the store-issue duty cycle. k-row index = g&127 constant per
// wave (reload only when batch changes, every 2 steps). -1-shifted aligned
// NT stores; shfl neighbor machinery; R==0 corner split to scalars.
// ---------------------------------------------------------------------------
__global__ __launch_bounds__(256) void main_kernel(
    const float* __restrict__ qbuf, const float* __restrict__ kbuf,
    const float* __restrict__ Wdec, const float* __restrict__ bdec,
    float* __restrict__ out)
{
    __shared__ float wcol[D_HIDDEN];
    __shared__ float red[4][64][16];
    __shared__ float rs[4];
    const int t  = threadIdx.x;
    const int bi = blockIdx.x;

    if (bi < SCORE_BLOCKS) {
        // ----------------------------- score -----------------------------
        const int sub = bi & 15;
        const int pr  = bi >> 4;
        const int n   = pr % NHEADS;
        const int b   = pr / NHEADS;

        for (int idx = t; idx < D_HIDDEN; idx += 256)
            wcol[idx] = Wdec[(size_t)idx * NHEADS + n];
        __syncthreads();

        const int qt   = (sub >> 2) * 32;
        const int kt   = (sub & 3) * 32;
        const int w    = t >> 6;
        const int lane = t & 63;
        const int lrow = lane & 15;
        const int koff = (lane >> 4) * 8;

        f32x4 acc[2][2];
        #pragma unroll
        for (int i = 0; i < 2; ++i)
            #pragma unroll
            for (int j = 0; j < 2; ++j) { f32x4 z = {0.f, 0.f, 0.f, 0.f}; acc[i][j] = z; }

        const float* qb = qbuf + (size_t)b * SEQ * D_HIDDEN;
        const float* kb = kbuf + (size_t)b * SEQ * D_HIDDEN;

        const int hlo = w * 512;
        for (int kk = hlo; kk < hlo + 512; kk += 32) {
            const int h0 = kk + koff;
            float wv[8];
            #pragma unroll
            for (int i = 0; i < 8; ++i) wv[i] = wcol[h0 + i];

            bf16x8 afrag[2], bfrag[2];
            #pragma unroll
            for (int fi = 0; fi < 2; ++fi) {
                const float* qp = qb + (size_t)(qt + fi * 16 + lrow) * D_HIDDEN + h0;
                const float4 q1 = *reinterpret_cast<const float4*>(qp);
                const float4 q2 = *reinterpret_cast<const float4*>(qp + 4);
                const float qf[8] = {q1.x, q1.y, q1.z, q1.w, q2.x, q2.y, q2.z, q2.w};
                #pragma unroll
                for (int i = 0; i < 8; ++i) afrag[fi][i] = (short)f2bf(qf[i] * wv[i]);
            }
            #pragma unroll
            for (int fj = 0; fj < 2; ++fj) {
                const float* kp = kb + (size_t)(kt + fj * 16 + lrow) * D_HIDDEN + h0;
                const float4 k1 = *reinterpret_cast<const float4*>(kp);
                const float4 k2 = *reinterpret_cast<const float4*>(kp + 4);
                const float kf[8] = {k1.x, k1.y, k1.z, k1.w, k2.x, k2.y, k2.z, k2.w};
                #pragma unroll
                for (int i = 0; i < 8; ++i) bfrag[fj][i] = (short)f2bf(kf[i]);
            }
            #pragma unroll
            for (int fi = 0; fi < 2; ++fi)
                #pragma unroll
                for (int fj = 0; fj < 2; ++fj)
                    acc[fi][fj] = __builtin_amdgcn_mfma_f32_16x16x32_bf16(
                        afrag[fi], bfrag[fj], acc[fi][fj], 0, 0, 0);
        }

        #pragma unroll
        for (int fi = 0; fi < 2; ++fi)
            #pragma unroll
            for (int fj = 0; fj < 2; ++fj)
                #pragma unroll
                for (int j = 0; j < 4; ++j)
                    red[w][lane][fi * 8 + fj * 4 + j] = acc[fi][fj][j];
        __syncthreads();

        const float bd   = bdec[n];
        const int   outb = (b * NHEADS + n) * SEQ * SEQ;
        #pragma unroll
        for (int u = 0; u < 4; ++u) {
            const int j = w * 4 + u;
            const float s = (red[0][lane][j] + red[1][lane][j])
                          + (red[2][lane][j] + red[3][lane][j]);
            const int fi = j >> 3, fj = (j >> 2) & 1, jj = j & 3;
            const int row = qt + fi * 16 + (lane >> 4) * 4 + jj;
            const int col = kt + fj * 16 + (lane & 15);
            out[outb + row * SEQ + col] = s * 0.125f + bd;
        }
        return;
    }

    // ------------------------------- fires -------------------------------
    const int w   = t >> 6;
    const int l   = t & 63;
    const int g   = (bi - SCORE_BLOCKS) * 4 + w;          // 0..8191
    const int gb7 = g >> 7;                                // 0..63
    const int gk  = g & 127;                               // k index (constant)

    f32x4* out4 = reinterpret_cast<f32x4*>(out + FIRES_OFF - 1);  // 16B aligned
    float racc = 0.f;

    #pragma unroll 1
    for (int b = 0; b < 4; ++b) {
        // k-row constant across the 2 steps of this batch
        const float* kr = kbuf + ((size_t)(b * SEQ) + gk) * D_HIDDEN;
        f32x4 kv[8];
        #pragma unroll
        for (int j = 0; j < 8; ++j)
            kv[j] = *reinterpret_cast<const f32x4*>(kr + 256 * j + 4 * l);
        float k3[8], k63[8];
        #pragma unroll
        for (int j = 0; j < 8; ++j) {
            k3[j]  = __shfl_up(kv[j][3], 1);
            k63[j] = __shfl(kv[j][3], 63);
        }

        #pragma unroll 1
        for (int half = 0; half < 2; ++half) {
            const int s    = b * 2 + half;
            const int R    = g + s * FIRES_WAVES;
            const int brow = s * 64 + gb7;                 // R >> 7
            const float* qr = qbuf + (size_t)brow * D_HIDDEN;

            f32x4 qv[8];
            #pragma unroll
            for (int j = 0; j < 8; ++j)
                qv[j] = *reinterpret_cast<const f32x4*>(qr + 256 * j + 4 * l);

            float pm1 = 0.f;
            if (l == 0 && R > 0) {
                const int pbrow = (R - 1) >> 7;
                const int pb    = pbrow >> 7;
                const int pkrow = (pb << 7) + ((R - 1) & 127);
                pm1 = qbuf[(size_t)pbrow * D_HIDDEN + 2047]
                    * kbuf[(size_t)pkrow * D_HIDDEN + 2047];
            }

            float q3[8], q63[8];
            #pragma unroll
            for (int j = 0; j < 8; ++j) {
                q3[j]  = __shfl_up(qv[j][3], 1);
                q63[j] = __shfl(qv[j][3], 63);
            }

            #pragma unroll
            for (int j = 0; j < 8; ++j) {
                float p0;
                if (l == 0) {
                    p0 = (j == 0) ? pm1 : q63[j - 1] * k63[j - 1];
                } else {
                    p0 = q3[j] * k3[j];
                }
                const float p1 = qv[j][0] * kv[j][0];
                const float p2 = qv[j][1] * kv[j][1];
                const float p3 = qv[j][2] * kv[j][2];
                f32x4 f;
                f[0] = (p0 > 0.f) ? 1.f : 0.f;
                f[1] = (p1 > 0.f) ? 1.f : 0.f;
                f[2] = (p2 > 0.f) ? 1.f : 0.f;
                f[3] = (p3 > 0.f) ? 1.f : 0.f;
                if (R == 0 && j == 0 && l == 0) {
                    // protect out[REG_OFF]: scalar stores of f[1..3] only
                    out[FIRES_OFF + 0] = f[1];
                    out[FIRES_OFF + 1] = f[2];
                    out[FIRES_OFF + 2] = f[3];
                } else {
                    __builtin_nontemporal_store(f, &out4[(size_t)R * 512 + 64 * j + l]);
                }
                racc += (fsqrt_fast(p0 + 1e-6f) + fsqrt_fast(p1 + 1e-6f))
                      + (fsqrt_fast(p2 + 1e-6f) + fsqrt_fast(p3 + 1e-6f));
            }
        }
    }

    // exclude the fake first slot's sqrt (R=0, j=0, l=0, p0 = 0)
    if (g == 0 && l == 0) racc -= fsqrt_fast(1e-6f);
    // global-last element (row 65535, h=2047)
    if (g == FIRES_WAVES - 1 && l == 0) {
        const float pv = qbuf[(size_t)511 * D_HIDDEN + 2047]
                       * kbuf[(size_t)511 * D_HIDDEN + 2047];
        out[(size_t)(FIRES_OFF - 1) + (size_t)NROWS_T * D_HIDDEN] = (pv > 0.f) ? 1.f : 0.f;
        racc += fsqrt_fast(pv + 1e-6f);
    }

    #pragma unroll
    for (int off = 32; off > 0; off >>= 1) racc += __shfl_down(racc, off);
    if (l == 0) rs[w] = racc;
    __syncthreads();
    if (t == 0)
        atomicAdd(out + REG_OFF, ((rs[0] + rs[1]) + (rs[2] + rs[3])) * 1e-3f);
}

// ---------------------------------------------------------------------------
extern "C" void kernel_launch(void* const* d_in, const int* in_sizes, int n_in,
                              void* d_out, int out_size, void* d_ws, size_t ws_size,
                              hipStream_t stream) {
    const float* x  = (const float*)d_in[0];
    const float* WQ = (const float*)d_in[1];
    const float* WK = (const float*)d_in[2];
    const float* bQ = (const float*)d_in[3];
    const float* bK = (const float*)d_in[4];
    const float* Wd = (const float*)d_in[5];
    const float* bd = (const float*)d_in[6];
    float* out  = (float*)d_out;
    float* qbuf = (float*)d_ws;                                // 4 MB
    float* kbuf = qbuf + (size_t)MROWS * D_HIDDEN;             // 4 MB

    dim3 b256(256);

    enc_kernel<<<dim3(D_HIDDEN / 64, MROWS / 64, 2), b256, 0, stream>>>(
        x, WQ, WK, bQ, bK, qbuf, kbuf, out);

    main_kernel<<<dim3(SCORE_BLOCKS + FIRES_BLOCKS), b256, 0, stream>>>(
        qbuf, kbuf, Wd, bd, out);
}